// Round 1
// baseline (2435.355 us; speedup 1.0000x reference)
//
#include <hip/hip_runtime.h>
#include <cmath>

typedef unsigned long long u64;

#define PRE_TOPN 12000
#define POST_TOPN 2000

// ---------------------------------------------------------------------------
// Kernel 1: decode boxes (exact fp32 op order as reference, no FMA contraction,
// exp via double = correctly-rounded f32 exp) and pack sort keys.
// key = (~score_bits)<<32 | idx  -> ascending sort == descending score,
// ties broken by ascending original index (matches stable argsort(-scores)).
// ---------------------------------------------------------------------------
__global__ void decode_pack(const float* __restrict__ anchors,
                            const float* __restrict__ deltas,
                            const float* __restrict__ scores,
                            float* __restrict__ boxes,
                            u64* __restrict__ keys,
                            int N, int SORTN) {
#pragma clang fp contract(off)
    int n = blockIdx.x * blockDim.x + threadIdx.x;
    int b = blockIdx.y;
    if (n >= SORTN) return;
    u64* kb = keys + (size_t)b * SORTN;
    if (n < N) {
        float a0 = anchors[n * 4 + 0];
        float a1 = anchors[n * 4 + 1];
        float a2 = anchors[n * 4 + 2];
        float a3 = anchors[n * 4 + 3];
        float w = (a2 - a0) + 1.0f;           // wh
        float h = (a3 - a1) + 1.0f;
        float cx = a0 + 0.5f * w;             // ctr
        float cy = a1 + 0.5f * h;
        const float* d = deltas + ((size_t)b * N + n) * 4;
        float dx = d[0], dy = d[1], dw = d[2], dh = d[3];
        float px = cx + w * dx;               // xys
        float py = cy + h * dy;
        float pw = (float)::exp((double)dw) * w;  // whs = exp(d)*wh
        float ph = (float)::exp((double)dh) * h;
        float* bb = boxes + ((size_t)b * N + n) * 4;
        bb[0] = px - 0.5f * pw;
        bb[1] = py - 0.5f * ph;
        bb[2] = px + 0.5f * (pw - 2.0f);
        bb[3] = py + 0.5f * (ph - 2.0f);
        unsigned int sb = __float_as_uint(scores[(size_t)b * N + n]);
        kb[n] = ((u64)(~sb) << 32) | (u64)(unsigned int)n;
    } else {
        kb[n] = ~0ULL;                        // pad sorts last
    }
}

// ---------------------------------------------------------------------------
// Kernel 2: per-batch bitonic sort of SORTN u64 keys, one block per batch,
// data in global memory (fits easily in L2). Keys are unique (idx in low
// bits) so unstable sort is fine.
// ---------------------------------------------------------------------------
__global__ __launch_bounds__(1024) void bitonic_sort(u64* __restrict__ keys, int SORTN) {
    u64* kb = keys + (size_t)blockIdx.x * SORTN;
    for (int k = 2; k <= SORTN; k <<= 1) {
        for (int j = k >> 1; j > 0; j >>= 1) {
            for (int i = threadIdx.x; i < SORTN; i += (int)blockDim.x) {
                int ixj = i ^ j;
                if (ixj > i) {
                    u64 a = kb[i];
                    u64 c = kb[ixj];
                    bool up = ((i & k) == 0);
                    if ((a > c) == up) { kb[i] = c; kb[ixj] = a; }
                }
            }
            __syncthreads();
        }
    }
}

// ---------------------------------------------------------------------------
// Kernel 3: greedy NMS per batch (one block, 1024 threads).
// Candidates processed in sorted order in chunks of 64.
//   Phase A: each chunk candidate checked vs all previously-kept boxes
//            (kept list in LDS, 16 threads per candidate).
//   Phase B: intra-chunk sequential greedy pass inside wave 0 via
//            ballot + shuffle; kept boxes appended to LDS list and the
//            ROI row written immediately (output order = pick order).
// Rows beyond the kept count are zeroed (matches invalid-row masking).
// ---------------------------------------------------------------------------
__global__ __launch_bounds__(1024) void nms_kernel(const float* __restrict__ boxes,
                                                   const u64* __restrict__ keys,
                                                   float* __restrict__ out,
                                                   int N, int SORTN) {
#pragma clang fp contract(off)
    __shared__ float kx1[POST_TOPN], ky1[POST_TOPN], kx2[POST_TOPN], ky2[POST_TOPN], kar[POST_TOPN];
    __shared__ float cx1s[64], cy1s[64], cx2s[64], cy2s[64], cars[64];
    __shared__ int supp[64];
    __shared__ int s_cnt;

    int b = blockIdx.x;
    int tid = threadIdx.x;
    const u64* kb = keys + (size_t)b * SORTN;
    const float* bb = boxes + (size_t)b * N * 4;

    if (tid == 0) s_cnt = 0;
    __syncthreads();

    for (int start = 0; start < PRE_TOPN; start += 64) {
        int K = s_cnt;                 // uniform (read after barrier)
        if (K >= POST_TOPN) break;     // uniform break
        int csize = min(64, PRE_TOPN - start);

        // load chunk
        if (tid < 64) {
            int c = tid;
            if (c < csize) {
                u64 key = kb[start + c];
                int n = (int)(unsigned int)(key & 0xFFFFFFFFULL);
                const float* p = bb + (size_t)n * 4;
                float x1 = p[0], y1 = p[1], x2 = p[2], y2 = p[3];
                cx1s[c] = x1; cy1s[c] = y1; cx2s[c] = x2; cy2s[c] = y2;
                cars[c] = ((x2 - x1) + 1.0f) * ((y2 - y1) + 1.0f);
            }
            supp[c] = 0;
        }
        __syncthreads();

        // Phase A: chunk vs kept list
        {
            int c = tid & 63;
            int sl = tid >> 6;         // 0..15
            if (c < csize) {
                float x1 = cx1s[c], y1 = cy1s[c], x2 = cx2s[c], y2 = cy2s[c], ar = cars[c];
                for (int kk = sl; kk < K; kk += 16) {
                    float xx1 = fmaxf(kx1[kk], x1);
                    float yy1 = fmaxf(ky1[kk], y1);
                    float xx2 = fminf(kx2[kk], x2);
                    float yy2 = fminf(ky2[kk], y2);
                    float w = fmaxf((xx2 - xx1) + 1.0f, 0.0f);
                    float h = fmaxf((yy2 - yy1) + 1.0f, 0.0f);
                    float inter = w * h;
                    float iou = inter / ((kar[kk] + ar) - inter);
                    if (iou > 0.7f) { supp[c] = 1; break; }
                }
            }
        }
        __syncthreads();

        // Phase B: intra-chunk sequential greedy (wave 0 only)
        if (tid < 64) {
            int c = tid;
            bool alive = (c < csize) && (supp[c] == 0);
            float x1 = cx1s[c], y1 = cy1s[c], x2 = cx2s[c], y2 = cy2s[c], ar = cars[c];
            int cnt = K;
            u64 m = __ballot(alive);
            while (m != 0 && cnt < POST_TOPN) {
                int i = __ffsll((unsigned long long)m) - 1;
                float ix1 = __shfl(x1, i);
                float iy1 = __shfl(y1, i);
                float ix2 = __shfl(x2, i);
                float iy2 = __shfl(y2, i);
                float iar = __shfl(ar, i);
                if (c == i) {
                    kx1[cnt] = x1; ky1[cnt] = y1; kx2[cnt] = x2; ky2[cnt] = y2; kar[cnt] = ar;
                    float* o = out + ((size_t)b * POST_TOPN + cnt) * 5;
                    o[0] = (float)b; o[1] = x1; o[2] = y1; o[3] = x2; o[4] = y2;
                }
                if (alive && c > i) {
                    float xx1 = fmaxf(ix1, x1);
                    float yy1 = fmaxf(iy1, y1);
                    float xx2 = fminf(ix2, x2);
                    float yy2 = fminf(iy2, y2);
                    float w = fmaxf((xx2 - xx1) + 1.0f, 0.0f);
                    float h = fmaxf((yy2 - yy1) + 1.0f, 0.0f);
                    float inter = w * h;
                    float iou = inter / ((iar + ar) - inter);
                    if (iou > 0.7f) alive = false;
                }
                cnt++;
                m = __ballot(alive);
                u64 clearmask = (2ULL << i) - 1ULL;   // bits 0..i (i==63 wraps -> all ones)
                m &= ~clearmask;
            }
            if (c == 0) s_cnt = cnt;
        }
        __syncthreads();
    }

    __syncthreads();
    int K = s_cnt;
    for (int r = K + tid; r < POST_TOPN; r += (int)blockDim.x) {
        float* o = out + ((size_t)b * POST_TOPN + r) * 5;
        o[0] = 0.0f; o[1] = 0.0f; o[2] = 0.0f; o[3] = 0.0f; o[4] = 0.0f;
    }
}

// ---------------------------------------------------------------------------
extern "C" void kernel_launch(void* const* d_in, const int* in_sizes, int n_in,
                              void* d_out, int out_size, void* d_ws, size_t ws_size,
                              hipStream_t stream) {
    const float* anchors = (const float*)d_in[0];
    const float* deltas  = (const float*)d_in[1];
    const float* scores  = (const float*)d_in[2];
    float* out = (float*)d_out;

    int N = in_sizes[0] / 4;           // 27380
    int B = in_sizes[2] / N;           // 8
    int SORTN = 1;
    while (SORTN < N) SORTN <<= 1;     // 32768

    float* boxes = (float*)d_ws;
    size_t boxesBytes = (size_t)B * N * 4 * sizeof(float);
    u64* keys = (u64*)((char*)d_ws + ((boxesBytes + 15) & ~(size_t)15));

    dim3 g1((unsigned)((SORTN + 255) / 256), (unsigned)B);
    decode_pack<<<g1, 256, 0, stream>>>(anchors, deltas, scores, boxes, keys, N, SORTN);
    bitonic_sort<<<B, 1024, 0, stream>>>(keys, SORTN);
    nms_kernel<<<B, 1024, 0, stream>>>(boxes, keys, out, N, SORTN);
}

// Round 2
// 1159.851 us; speedup vs baseline: 2.0997x; 2.0997x over previous
//
#include <hip/hip_runtime.h>
#include <cmath>

typedef unsigned long long u64;

#define PRE_TOPN 12000
#define POST_TOPN 2000
#define SORTN 32768
#define TILE 8192
#define NTILE (SORTN / TILE)   // 4 tiles per batch

// ---------------------------------------------------------------------------
// Kernel 1: decode boxes (exact fp32 op order as reference, no FMA contraction,
// exp via double = correctly-rounded f32 exp) and pack sort keys.
// key = (~score_bits)<<32 | idx  -> ascending sort == descending score,
// ties broken by ascending original index (matches stable argsort(-scores)).
// ---------------------------------------------------------------------------
__global__ void decode_pack(const float* __restrict__ anchors,
                            const float* __restrict__ deltas,
                            const float* __restrict__ scores,
                            float* __restrict__ boxes,
                            u64* __restrict__ keys,
                            int N) {
#pragma clang fp contract(off)
    int n = blockIdx.x * blockDim.x + threadIdx.x;
    int b = blockIdx.y;
    if (n >= SORTN) return;
    u64* kb = keys + (size_t)b * SORTN;
    if (n < N) {
        float a0 = anchors[n * 4 + 0];
        float a1 = anchors[n * 4 + 1];
        float a2 = anchors[n * 4 + 2];
        float a3 = anchors[n * 4 + 3];
        float w = (a2 - a0) + 1.0f;           // wh
        float h = (a3 - a1) + 1.0f;
        float cx = a0 + 0.5f * w;             // ctr
        float cy = a1 + 0.5f * h;
        const float* d = deltas + ((size_t)b * N + n) * 4;
        float dx = d[0], dy = d[1], dw = d[2], dh = d[3];
        float px = cx + w * dx;               // xys
        float py = cy + h * dy;
        float pw = (float)::exp((double)dw) * w;  // whs = exp(d)*wh
        float ph = (float)::exp((double)dh) * h;
        float* bb = boxes + ((size_t)b * N + n) * 4;
        bb[0] = px - 0.5f * pw;
        bb[1] = py - 0.5f * ph;
        bb[2] = px + 0.5f * (pw - 2.0f);
        bb[3] = py + 0.5f * (ph - 2.0f);
        unsigned int sb = __float_as_uint(scores[(size_t)b * N + n]);
        kb[n] = ((u64)(~sb) << 32) | (u64)(unsigned int)n;
    } else {
        kb[n] = ~0ULL;                        // pad sorts last
    }
}

// ---------------------------------------------------------------------------
// Hybrid bitonic sort. Tiles of TILE=8192 u64 keys live in 64 KB LDS.
// Stage directions use the GLOBAL index (base+i), so tile parity gives the
// alternating ascending/descending runs bitonic merging needs.
// ---------------------------------------------------------------------------
__global__ __launch_bounds__(1024) void bitonic_local_sort(u64* __restrict__ keys) {
    __shared__ u64 sk[TILE];
    int tile = blockIdx.x;                        // global tile id (B*NTILE)
    u64* kb = keys + (size_t)tile * TILE;
    int base = (tile % NTILE) * TILE;             // offset within batch
    for (int i = threadIdx.x; i < TILE; i += 1024) sk[i] = kb[i];
    __syncthreads();
    for (int k = 2; k <= TILE; k <<= 1) {
        for (int j = k >> 1; j > 0; j >>= 1) {
            for (int t = threadIdx.x; t < TILE / 2; t += 1024) {
                int i = ((t & ~(j - 1)) << 1) | (t & (j - 1));
                int ixj = i | j;
                u64 a = sk[i];
                u64 c = sk[ixj];
                bool up = (((base + i) & k) == 0);
                if ((a > c) == up) { sk[i] = c; sk[ixj] = a; }
            }
            __syncthreads();
        }
    }
    for (int i = threadIdx.x; i < TILE; i += 1024) kb[i] = sk[i];
}

// one global compare-exchange pass (j >= TILE)
__global__ void bitonic_global_step(u64* __restrict__ keys, int k, int j) {
    int t = blockIdx.x * blockDim.x + threadIdx.x;   // over B*SORTN/2
    int b = t / (SORTN / 2);
    int s = t % (SORTN / 2);
    int i = ((s & ~(j - 1)) << 1) | (s & (j - 1));
    int ixj = i | j;
    u64* kb = keys + (size_t)b * SORTN;
    u64 a = kb[i];
    u64 c = kb[ixj];
    bool up = ((i & k) == 0);
    if ((a > c) == up) { kb[i] = c; kb[ixj] = a; }
}

// remaining j = TILE/2 .. 1 for stage k (k > TILE): direction uniform per tile
__global__ __launch_bounds__(1024) void bitonic_local_merge(u64* __restrict__ keys, int k) {
    __shared__ u64 sk[TILE];
    int tile = blockIdx.x;
    u64* kb = keys + (size_t)tile * TILE;
    int base = (tile % NTILE) * TILE;
    bool up = ((base & k) == 0);                  // k > TILE -> uniform in tile
    for (int i = threadIdx.x; i < TILE; i += 1024) sk[i] = kb[i];
    __syncthreads();
    for (int j = TILE / 2; j > 0; j >>= 1) {
        for (int t = threadIdx.x; t < TILE / 2; t += 1024) {
            int i = ((t & ~(j - 1)) << 1) | (t & (j - 1));
            int ixj = i | j;
            u64 a = sk[i];
            u64 c = sk[ixj];
            if ((a > c) == up) { sk[i] = c; sk[ixj] = a; }
        }
        __syncthreads();
    }
    for (int i = threadIdx.x; i < TILE; i += 1024) kb[i] = sk[i];
}

// ---------------------------------------------------------------------------
// Kernel 3: greedy NMS per batch (one block, 1024 threads).
// Kept boxes packed as float4 (one ds_read_b128 per check) + area array.
// Phase A unrolled x2 for LDS-load ILP.
// ---------------------------------------------------------------------------
__global__ __launch_bounds__(1024) void nms_kernel(const float* __restrict__ boxes,
                                                   const u64* __restrict__ keys,
                                                   float* __restrict__ out,
                                                   int N) {
#pragma clang fp contract(off)
    __shared__ float4 kbox[POST_TOPN];
    __shared__ float kar[POST_TOPN];
    __shared__ float4 cbox[64];
    __shared__ float car_s[64];
    __shared__ int supp[64];
    __shared__ int s_cnt;

    int b = blockIdx.x;
    int tid = threadIdx.x;
    const u64* kb = keys + (size_t)b * SORTN;
    const float* bb = boxes + (size_t)b * N * 4;

    if (tid == 0) s_cnt = 0;
    __syncthreads();

    for (int start = 0; start < PRE_TOPN; start += 64) {
        int K = s_cnt;                 // uniform (read after barrier)
        if (K >= POST_TOPN) break;     // uniform break
        int csize = min(64, PRE_TOPN - start);

        // load chunk
        if (tid < 64) {
            int c = tid;
            if (c < csize) {
                u64 key = kb[start + c];
                int n = (int)(unsigned int)(key & 0xFFFFFFFFULL);
                const float* p = bb + (size_t)n * 4;
                float x1 = p[0], y1 = p[1], x2 = p[2], y2 = p[3];
                cbox[c] = make_float4(x1, y1, x2, y2);
                car_s[c] = ((x2 - x1) + 1.0f) * ((y2 - y1) + 1.0f);
            }
            supp[c] = 0;
        }
        __syncthreads();

        // Phase A: chunk vs kept list (16 sub-threads per candidate)
        {
            int c = tid & 63;
            int sl = tid >> 6;         // 0..15
            if (c < csize) {
                float4 me = cbox[c];
                float ar = car_s[c];
                int flag = 0;
                int kk = sl;
                for (; kk + 16 < K; kk += 32) {
                    float4 k0 = kbox[kk];
                    float a0 = kar[kk];
                    float4 k1 = kbox[kk + 16];
                    float a1 = kar[kk + 16];
                    float xx1 = fmaxf(k0.x, me.x);
                    float yy1 = fmaxf(k0.y, me.y);
                    float xx2 = fminf(k0.z, me.z);
                    float yy2 = fminf(k0.w, me.w);
                    float w0 = fmaxf((xx2 - xx1) + 1.0f, 0.0f);
                    float h0 = fmaxf((yy2 - yy1) + 1.0f, 0.0f);
                    float inter0 = w0 * h0;
                    float iou0 = inter0 / ((a0 + ar) - inter0);
                    float ux1 = fmaxf(k1.x, me.x);
                    float uy1 = fmaxf(k1.y, me.y);
                    float ux2 = fminf(k1.z, me.z);
                    float uy2 = fminf(k1.w, me.w);
                    float w1 = fmaxf((ux2 - ux1) + 1.0f, 0.0f);
                    float h1 = fmaxf((uy2 - uy1) + 1.0f, 0.0f);
                    float inter1 = w1 * h1;
                    float iou1 = inter1 / ((a1 + ar) - inter1);
                    if (iou0 > 0.7f || iou1 > 0.7f) { flag = 1; break; }
                }
                if (!flag) {
                    for (; kk < K; kk += 16) {
                        float4 k0 = kbox[kk];
                        float a0 = kar[kk];
                        float xx1 = fmaxf(k0.x, me.x);
                        float yy1 = fmaxf(k0.y, me.y);
                        float xx2 = fminf(k0.z, me.z);
                        float yy2 = fminf(k0.w, me.w);
                        float w0 = fmaxf((xx2 - xx1) + 1.0f, 0.0f);
                        float h0 = fmaxf((yy2 - yy1) + 1.0f, 0.0f);
                        float inter0 = w0 * h0;
                        float iou0 = inter0 / ((a0 + ar) - inter0);
                        if (iou0 > 0.7f) { flag = 1; break; }
                    }
                }
                if (flag) supp[c] = 1;
            }
        }
        __syncthreads();

        // Phase B: intra-chunk sequential greedy (wave 0 only)
        if (tid < 64) {
            int c = tid;
            bool alive = (c < csize) && (supp[c] == 0);
            float4 me = cbox[c];
            float ar = car_s[c];
            int cnt = K;
            u64 m = __ballot(alive);
            while (m != 0 && cnt < POST_TOPN) {
                int i = __ffsll((unsigned long long)m) - 1;
                float ix1 = __shfl(me.x, i);
                float iy1 = __shfl(me.y, i);
                float ix2 = __shfl(me.z, i);
                float iy2 = __shfl(me.w, i);
                float iar = __shfl(ar, i);
                if (c == i) {
                    kbox[cnt] = me;
                    kar[cnt] = ar;
                    float* o = out + ((size_t)b * POST_TOPN + cnt) * 5;
                    o[0] = (float)b; o[1] = me.x; o[2] = me.y; o[3] = me.z; o[4] = me.w;
                }
                if (alive && c > i) {
                    float xx1 = fmaxf(ix1, me.x);
                    float yy1 = fmaxf(iy1, me.y);
                    float xx2 = fminf(ix2, me.z);
                    float yy2 = fminf(iy2, me.w);
                    float w = fmaxf((xx2 - xx1) + 1.0f, 0.0f);
                    float h = fmaxf((yy2 - yy1) + 1.0f, 0.0f);
                    float inter = w * h;
                    float iou = inter / ((iar + ar) - inter);
                    if (iou > 0.7f) alive = false;
                }
                cnt++;
                m = __ballot(alive);
                u64 clearmask = (2ULL << i) - 1ULL;   // bits 0..i
                m &= ~clearmask;
            }
            if (c == 0) s_cnt = cnt;
        }
        __syncthreads();
    }

    __syncthreads();
    int K = s_cnt;
    for (int r = K + tid; r < POST_TOPN; r += (int)blockDim.x) {
        float* o = out + ((size_t)b * POST_TOPN + r) * 5;
        o[0] = 0.0f; o[1] = 0.0f; o[2] = 0.0f; o[3] = 0.0f; o[4] = 0.0f;
    }
}

// ---------------------------------------------------------------------------
extern "C" void kernel_launch(void* const* d_in, const int* in_sizes, int n_in,
                              void* d_out, int out_size, void* d_ws, size_t ws_size,
                              hipStream_t stream) {
    const float* anchors = (const float*)d_in[0];
    const float* deltas  = (const float*)d_in[1];
    const float* scores  = (const float*)d_in[2];
    float* out = (float*)d_out;

    int N = in_sizes[0] / 4;           // 27380
    int B = in_sizes[2] / N;           // 8

    float* boxes = (float*)d_ws;
    size_t boxesBytes = (size_t)B * N * 4 * sizeof(float);
    u64* keys = (u64*)((char*)d_ws + ((boxesBytes + 15) & ~(size_t)15));

    dim3 g1((unsigned)((SORTN + 255) / 256), (unsigned)B);
    decode_pack<<<g1, 256, 0, stream>>>(anchors, deltas, scores, boxes, keys, N);

    int ntiles = B * NTILE;                          // 32
    bitonic_local_sort<<<ntiles, 1024, 0, stream>>>(keys);
    int gsteps = B * (SORTN / 2) / 256;              // 512 blocks
    bitonic_global_step<<<gsteps, 256, 0, stream>>>(keys, 2 * TILE, TILE);
    bitonic_local_merge<<<ntiles, 1024, 0, stream>>>(keys, 2 * TILE);
    bitonic_global_step<<<gsteps, 256, 0, stream>>>(keys, 4 * TILE, 2 * TILE);
    bitonic_global_step<<<gsteps, 256, 0, stream>>>(keys, 4 * TILE, TILE);
    bitonic_local_merge<<<ntiles, 1024, 0, stream>>>(keys, 4 * TILE);

    nms_kernel<<<B, 1024, 0, stream>>>(boxes, keys, out, N);
}